// Round 2
// baseline (222.735 us; speedup 1.0000x reference)
//
#include <hip/hip_runtime.h>
#include <math.h>

// ---------------------------------------------------------------------------
// Deep4Net, fully fused: one block per sample, all activations LDS-resident.
// conv1+conv2 fused algebraically (prep kernel); pool(elu)=elu(pool).
// Each K=10 conv = 10 accumulated GEMMs over input channels:
//   out[o][t] += sum_i wk[k][o][i] * xT[t+k][i]
// A-frag: wk[k][o=lane&15 (+tile)][i: quad*8..+7]   (global, L2-hot)
// B-frag: xT[t][i: quad*8..+7]                      (LDS ds_read_b128)
//
// LDS overlay (121.6 KB peak; xsAll dead after conv12, so P2/P3/feats
// reuse its region):
//   [     0..72000)  xsAll [1000][36] bf16 (conv12 in)   | P2 [107][68] bf16
//                                                        | P3 @16000 [32][132]
//                                                        | feats @25600 f32
//   [ 72000..95760)  P1 [330][36] bf16   (conv12 out / conv3 in)
//   [ 95760..124560) sc f32 scratch      (C-frag transpose, all layers)
// Workspace: float region (biases) then short(bf16) region (weights).
#define F_BC   0         // 32   combined bias (padded)
#define F_B2   32        // 64
#define F_B3   96        // 128
#define F_B4   224       // 224
#define SHORT_BASE 896   // short index of bf16 region (448 f32 * 2)
#define WK12   0         // [10][32][32]
#define WK3    10240     // [10][64][32]
#define WK4    30720     // [10][128][64]
#define WK5    112640    // [10][224][128]
// ---------------------------------------------------------------------------

typedef __attribute__((ext_vector_type(8))) short short8;
typedef __attribute__((ext_vector_type(4))) float f32x4;

__device__ __forceinline__ short f2bf(float f) {
    union { float f; unsigned u; } v; v.f = f;
    unsigned r = v.u + 0x7FFF + ((v.u >> 16) & 1);
    return (short)(r >> 16);
}

// ---- K0: weight prep (combine conv1/2, transpose+pad all to bf16) ---------
__global__ __launch_bounds__(256) void k_prep2(
    const float* __restrict__ wt, const float* __restrict__ bt,
    const float* __restrict__ wsp, const float* __restrict__ bsp,
    const float* __restrict__ w2, const float* __restrict__ b2,
    const float* __restrict__ w3, const float* __restrict__ b3,
    const float* __restrict__ w4, const float* __restrict__ b4,
    float* __restrict__ wsf, short* __restrict__ wss) {
    int idx = blockIdx.x * 256 + threadIdx.x;
    if (idx < 448) {                           // padded biases (f32)
        float v = 0.f;
        if (idx < 32) {
            int o = idx;
            if (o < 25) {
                v = bsp[o];
                for (int i = 0; i < 25; ++i) {
                    float rs = 0.f;
                    for (int c = 0; c < 22; ++c) rs += wsp[(o * 25 + i) * 22 + c];
                    v += bt[i] * rs;
                }
            }
        } else if (idx < 96)  { int o = idx - 32;  v = (o < 50)  ? b2[o] : 0.f; }
        else if (idx < 224)   { int o = idx - 96;  v = (o < 100) ? b3[o] : 0.f; }
        else                  { int o = idx - 224; v = (o < 200) ? b4[o] : 0.f; }
        wsf[idx] = v;
        return;
    }
    int j = idx - 448;
    if (j < 10240) {                           // wk12 [k][32][32] (combined)
        int k = j / 1024, o = (j / 32) % 32, i = j % 32;
        float v = 0.f;
        if (o < 25 && i < 22)
            for (int q = 0; q < 25; ++q) v += wt[q * 10 + k] * wsp[(o * 25 + q) * 22 + i];
        wss[WK12 + j] = f2bf(v);
        return;
    }
    j -= 10240;
    if (j < 20480) {                           // wk3 [k][64][32]
        int k = j / 2048, o = (j / 32) % 64, i = j % 32;
        float v = (o < 50 && i < 25) ? w2[(o * 25 + i) * 10 + k] : 0.f;
        wss[WK3 + j] = f2bf(v);
        return;
    }
    j -= 20480;
    if (j < 81920) {                           // wk4 [k][128][64]
        int k = j / 8192, o = (j / 64) % 128, i = j % 64;
        float v = (o < 100 && i < 50) ? w3[(o * 50 + i) * 10 + k] : 0.f;
        wss[WK4 + j] = f2bf(v);
        return;
    }
    j -= 81920;
    if (j < 286720) {                          // wk5 [k][224][128]
        int k = j / 28672, o = (j / 128) % 224, i = j % 128;
        float v = (o < 200 && i < 100) ? w4[(o * 100 + i) * 10 + k] : 0.f;
        wss[WK5 + j] = f2bf(v);
    }
}

// ---- generic MFMA conv+pool+ELU layer, LDS->LDS, inside fused kernel ------
// 8 waves decomposed WMW x WNW; each active wave owns MTW x NTW 16x16 tiles.
// xin stride IPAD+4 (<=2-way or conflict-free rows); sc stride OPAD+1 (odd,
// conflict-free for both C-frag writes and pooled reads).
template<int OPAD, int IPAD, int IB, int WMW, int WNW, int MTW, int NTW,
         int NCHUNK, int NC, int TIN, int NPtot, bool LAST>
__device__ __forceinline__ void conv_layer(
    const short* __restrict__ wk, const float* __restrict__ bias,
    const short* xin, short* outT, float* feats, float* sc, int tid) {
    constexpr int XSTR = IPAD + 4;
    constexpr int OSTR = OPAD + 4;
    constexpr int SSTR = OPAD + 1;
    constexpr int PCc  = NCHUNK / 3;

    int w = tid >> 6, lane = tid & 63, l15 = lane & 15, quad = lane >> 4;
    bool act = (w < WMW * WNW);
    int mBase = (w % WMW) * MTW * 16;
    int nBase = (w / WMW) * NTW * 16;

    for (int nc = 0; nc < NC; ++nc) {
        int t0 = nc * NCHUNK;
        if (act) {
            f32x4 acc[MTW][NTW];
#pragma unroll
            for (int mi = 0; mi < MTW; ++mi)
#pragma unroll
                for (int ni = 0; ni < NTW; ++ni)
                    acc[mi][ni] = (f32x4){0.f, 0.f, 0.f, 0.f};

#pragma unroll 2
            for (int k = 0; k < 10; ++k) {
#pragma unroll
                for (int ib = 0; ib < IB; ++ib) {
                    short8 bf[NTW];
#pragma unroll
                    for (int ni = 0; ni < NTW; ++ni) {
                        int t = t0 + nBase + ni * 16 + l15 + k;
                        if (t >= TIN) t = TIN - 1;   // clamp; extras discarded
                        bf[ni] = *(const short8*)(xin + t * XSTR + ib * 32 + quad * 8);
                    }
#pragma unroll
                    for (int mi = 0; mi < MTW; ++mi) {
                        short8 a = *(const short8*)(wk + (size_t)k * OPAD * IPAD +
                                                    (mBase + mi * 16 + l15) * IPAD +
                                                    ib * 32 + quad * 8);
#pragma unroll
                        for (int ni = 0; ni < NTW; ++ni)
                            acc[mi][ni] = __builtin_amdgcn_mfma_f32_16x16x32_bf16(
                                a, bf[ni], acc[mi][ni], 0, 0, 0);
                    }
                }
            }
            // C frags -> sc transposed: sc[col_local][o]
#pragma unroll
            for (int mi = 0; mi < MTW; ++mi)
#pragma unroll
                for (int ni = 0; ni < NTW; ++ni) {
                    int col = nBase + ni * 16 + l15;
                    int rb = mBase + mi * 16 + quad * 4;
#pragma unroll
                    for (int r = 0; r < 4; ++r)
                        sc[col * SSTR + rb + r] = acc[mi][ni][r];
                }
        }
        __syncthreads();
        // pool3 + bias + ELU + store (bf16 time-major LDS, or f32 feats)
        int pc0 = nc * PCc;
        for (int i = tid; i < PCc * OPAD; i += 512) {
            int tp = i / OPAD, ol = i - tp * OPAD;
            if (pc0 + tp < NPtot) {
                float s0 = sc[(tp * 3 + 0) * SSTR + ol];
                float s1 = sc[(tp * 3 + 1) * SSTR + ol];
                float s2 = sc[(tp * 3 + 2) * SSTR + ol];
                float m = fmaxf(fmaxf(s0, s1), s2) + bias[ol];
                float e = m > 0.f ? m : __expf(m) - 1.f;
                if constexpr (LAST) {
                    if (ol < 200) feats[ol * 7 + pc0 + tp] = e;
                } else {
                    outT[(pc0 + tp) * OSTR + ol] = f2bf(e);
                }
            }
        }
        __syncthreads();
    }
}

// ---- fused backbone + head: one block per sample --------------------------
// LDS overlay offsets (bytes); all 16-aligned. Peak 124,560 B (121.6 KB).
#define OFF_P2   0        // [107][68] bf16, live conv3-out .. conv4-in
#define OFF_P3   16000    // [32][132] bf16, live conv4-out .. conv5-in
#define OFF_FE   25600    // [1400] f32,     live conv5-out .. head
#define OFF_P1   72000    // [330][36] bf16, live conv12-out .. conv3-in
#define OFF_SC   95760    // f32 scratch (28800 B), reused by all layers
#define LDS_TOT  124560

__global__ __launch_bounds__(512, 1) void k_fused(
    const float* __restrict__ x, const int* __restrict__ sid,
    const short* __restrict__ wss, const float* __restrict__ wsf,
    const float* __restrict__ hW, const float* __restrict__ hB,
    float* __restrict__ out) {
    __shared__ __align__(16) unsigned char ldsbuf[LDS_TOT];
    short* xsAll = (short*)ldsbuf;              // [1000][36], dead after conv12
    short* P2    = (short*)(ldsbuf + OFF_P2);
    short* P3    = (short*)(ldsbuf + OFF_P3);
    float* feats = (float*)(ldsbuf + OFF_FE);
    short* P1    = (short*)(ldsbuf + OFF_P1);
    float* sc    = (float*)(ldsbuf + OFF_SC);

    int b = blockIdx.x;
    int tid = threadIdx.x;

    // ---- stage x[b] f32 [22][1000] -> xsAll bf16 time-major [1000][36] ----
    const float4* xb4 = reinterpret_cast<const float4*>(x + (size_t)b * 22000);
    for (int i = tid; i < 5500; i += 512) {     // 22 ch * 250 float4
        int c = i / 250, t4 = (i - c * 250) * 4;
        float4 v = xb4[i];
        xsAll[(t4 + 0) * 36 + c] = f2bf(v.x);
        xsAll[(t4 + 1) * 36 + c] = f2bf(v.y);
        xsAll[(t4 + 2) * 36 + c] = f2bf(v.z);
        xsAll[(t4 + 3) * 36 + c] = f2bf(v.w);
    }
    for (int i = tid; i < 10000; i += 512) {    // zero pad channels 22..31
        int c = 22 + i / 1000, t = i % 1000;
        xsAll[t * 36 + c] = 0;
    }
    __syncthreads();

    // conv12: M=32(25), N=990 -> 330 pooled; 6 chunks of 192
    conv_layer<32, 32, 1, 2, 4, 1, 3, 192, 6, 1000, 330, false>(
        wss + WK12, wsf + F_BC, xsAll, P1, nullptr, sc, tid);
    // conv3: M=64(50), N=321 -> 107 pooled; 4 chunks of 96
    conv_layer<64, 32, 1, 4, 2, 1, 3, 96, 4, 330, 107, false>(
        wss + WK3, wsf + F_B2, P1, P2, nullptr, sc, tid);
    // conv4: M=128(100), N=96 -> 32 pooled; 2 chunks of 48
    conv_layer<128, 64, 2, 8, 1, 1, 3, 48, 2, 107, 32, false>(
        wss + WK4, wsf + F_B3, P2, P3, nullptr, sc, tid);
    // conv5: M=224(200), N=21 -> 7 pooled; 1 chunk of 32 (waves 0-6 active)
    conv_layer<224, 128, 4, 7, 1, 2, 2, 32, 1, 32, 7, true>(
        wss + WK5, wsf + F_B4, P3, nullptr, feats, sc, tid);

    // ---- head: per-sample routed linear, wave w -> output w (w<4) ----
    int w = tid >> 6, lane = tid & 63;
    if (w < 4) {
        int s = sid[b];
        const float4* wrow = reinterpret_cast<const float4*>(hW + (size_t)(s * 4 + w) * 1400);
        const float4* fv = reinterpret_cast<const float4*>(feats);
        float acc = 0.f;
        for (int f = lane; f < 350; f += 64) {
            float4 a = wrow[f], c = fv[f];
            acc += a.x * c.x + a.y * c.y + a.z * c.z + a.w * c.w;
        }
#pragma unroll
        for (int off = 32; off; off >>= 1) acc += __shfl_down(acc, off);
        if (lane == 0) out[b * 4 + w] = acc + hB[s * 4 + w];
    }
}

extern "C" void kernel_launch(void* const* d_in, const int* in_sizes, int n_in,
                              void* d_out, int out_size, void* d_ws, size_t ws_size,
                              hipStream_t stream) {
    const float* x   = (const float*)d_in[0];
    const int*   sid = (const int*)d_in[1];
    const float* wt  = (const float*)d_in[2];
    const float* bt  = (const float*)d_in[3];
    const float* wsp = (const float*)d_in[4];
    const float* bsp = (const float*)d_in[5];
    const float* w2  = (const float*)d_in[6];
    const float* b2  = (const float*)d_in[7];
    const float* w3  = (const float*)d_in[8];
    const float* b3  = (const float*)d_in[9];
    const float* w4  = (const float*)d_in[10];
    const float* b4  = (const float*)d_in[11];
    const float* hW  = (const float*)d_in[12];
    const float* hB  = (const float*)d_in[13];
    float* out = (float*)d_out;
    float* wsf = (float*)d_ws;
    short* wss = (short*)d_ws + SHORT_BASE;

    // prep: 448 + 10240 + 20480 + 81920 + 286720 = 399808 elements
    k_prep2<<<1562, 256, 0, stream>>>(wt, bt, wsp, bsp, w2, b2, w3, b3, w4, b4,
                                      wsf, wss);
    // fused backbone + head: 1 block per sample, 8 waves, 121.6 KB LDS
    k_fused<<<256, 512, 0, stream>>>(x, sid, wss, wsf, hW, hB, out);
}

// Round 3
// 216.104 us; speedup vs baseline: 1.0307x; 1.0307x over previous
//
#include <hip/hip_runtime.h>
#include <math.h>

// ---------------------------------------------------------------------------
// Deep4Net, fully fused: one block per sample, all activations LDS-resident.
// conv1+conv2 fused algebraically (prep kernel); pool(elu)=elu(pool).
// Each K=10 conv = 10 accumulated GEMMs over input channels:
//   out[o][t] += sum_i wk[k][o][i] * xT[t+k][i]
// Weights are stored FRAGMENT-ORDERED by prep: for each (k, ib, otile) a
// 512-short block where lane l holds shorts [l*8..l*8+7] = its exact MFMA
// A-fragment -> each wave A-load is one coalesced 1KB global_load_dwordx4.
// B-frag: xT[t][i: quad*8..+7] from LDS (ds_read_b128, padded rows).
// Inner loop: explicit depth-1 ping-pong prefetch (a0/b0 vs a1/b1) so the
// next (k,ib) step's global+LDS loads overlap the current MFMA cluster.
//
// LDS overlay (121.6 KB peak; xsAll dead after conv12, so P2/P3/feats
// reuse its region):
//   [     0..72000)  xsAll [1000][36] bf16 (conv12 in)   | P2 [107][68] bf16
//                                                        | P3 @16000 [32][132]
//                                                        | feats @25600 f32
//   [ 72000..95760)  P1 [330][36] bf16   (conv12 out / conv3 in)
//   [ 95760..124560) sc f32 scratch      (C-frag transpose, all layers)
// Workspace: float region (biases) then short(bf16) region (weights).
#define F_BC   0         // 32   combined bias (padded)
#define F_B2   32        // 64
#define F_B3   96        // 128
#define F_B4   224       // 224
#define SHORT_BASE 896   // short index of bf16 region (448 f32 * 2)
#define WK12   0         // [10][1][2][512]   (k, ib, otile, frag)
#define WK3    10240     // [10][1][4][512]
#define WK4    30720     // [10][2][8][512]
#define WK5    112640    // [10][4][14][512]
// ---------------------------------------------------------------------------

typedef __attribute__((ext_vector_type(8))) short short8;
typedef __attribute__((ext_vector_type(4))) float f32x4;

__device__ __forceinline__ short f2bf(float f) {
    union { float f; unsigned u; } v; v.f = f;
    unsigned r = v.u + 0x7FFF + ((v.u >> 16) & 1);
    return (short)(r >> 16);
}

// ---- K0: weight prep --------------------------------------------------------
// block 0: biases (combined conv1/2 bias via LDS-atomic reduction over 625
// (o,i) pairs -- the old serial 25-thread version was ~70us!).
// blocks 1..1560: fragment-ordered bf16 weight transpose (399360 elems).
__global__ __launch_bounds__(256) void k_prep2(
    const float* __restrict__ wt, const float* __restrict__ bt,
    const float* __restrict__ wsp, const float* __restrict__ bsp,
    const float* __restrict__ w2, const float* __restrict__ b2,
    const float* __restrict__ w3, const float* __restrict__ b3,
    const float* __restrict__ w4, const float* __restrict__ b4,
    float* __restrict__ wsf, short* __restrict__ wss) {
    int tid = threadIdx.x;
    if (blockIdx.x == 0) {
        __shared__ float bacc[32];
        if (tid < 32) bacc[tid] = 0.f;
        __syncthreads();
        for (int p = tid; p < 625; p += 256) {      // combined bias reduction
            int o = p / 25, i = p - o * 25;
            float rs = 0.f;
            for (int c = 0; c < 22; ++c) rs += wsp[(o * 25 + i) * 22 + c];
            atomicAdd(&bacc[o], bt[i] * rs);
        }
        __syncthreads();
        for (int idx = tid; idx < 448; idx += 256) {
            float v;
            if (idx < 32)        v = (idx < 25) ? bsp[idx] + bacc[idx] : 0.f;
            else if (idx < 96)  { int o = idx - 32;  v = (o < 50)  ? b2[o] : 0.f; }
            else if (idx < 224) { int o = idx - 96;  v = (o < 100) ? b3[o] : 0.f; }
            else                { int o = idx - 224; v = (o < 200) ? b4[o] : 0.f; }
            wsf[idx] = v;
        }
        return;
    }
    int j = (blockIdx.x - 1) * 256 + tid;
    if (j < 10240) {                           // wk12 combined: OPAD=32, IB=1
        int g = j >> 9, s = j & 511;
        int k = g >> 1, ot = g & 1;
        int lane = s >> 3, e = s & 7;
        int o = ot * 16 + (lane & 15), i = (lane >> 4) * 8 + e;
        float v = 0.f;
        if (o < 25 && i < 22)
            for (int q = 0; q < 25; ++q) v += wt[q * 10 + k] * wsp[(o * 25 + q) * 22 + i];
        wss[WK12 + j] = f2bf(v);
        return;
    }
    j -= 10240;
    if (j < 20480) {                           // wk3: OPAD=64, IB=1 (4 blk/k)
        int g = j >> 9, s = j & 511;
        int k = g >> 2, ot = g & 3;
        int lane = s >> 3, e = s & 7;
        int o = ot * 16 + (lane & 15), i = (lane >> 4) * 8 + e;
        float v = (o < 50 && i < 25) ? w2[(o * 25 + i) * 10 + k] : 0.f;
        wss[WK3 + j] = f2bf(v);
        return;
    }
    j -= 20480;
    if (j < 81920) {                           // wk4: OPAD=128, IB=2 (16 blk/k)
        int g = j >> 9, s = j & 511;
        int k = g >> 4, rem = g & 15, ib = rem >> 3, ot = rem & 7;
        int lane = s >> 3, e = s & 7;
        int o = ot * 16 + (lane & 15), i = ib * 32 + (lane >> 4) * 8 + e;
        float v = (o < 100 && i < 50) ? w3[(o * 50 + i) * 10 + k] : 0.f;
        wss[WK4 + j] = f2bf(v);
        return;
    }
    j -= 81920;
    if (j < 286720) {                          // wk5: OPAD=224, IB=4 (56 blk/k)
        int g = j >> 9, s = j & 511;
        int k = g / 56, rem = g % 56, ib = rem / 14, ot = rem % 14;
        int lane = s >> 3, e = s & 7;
        int o = ot * 16 + (lane & 15), i = ib * 32 + (lane >> 4) * 8 + e;
        float v = (o < 200 && i < 100) ? w4[(o * 100 + i) * 10 + k] : 0.f;
        wss[WK5 + j] = f2bf(v);
    }
}

// ---- generic MFMA conv+pool+ELU layer, LDS->LDS, inside fused kernel ------
// 8 waves decomposed WMW x WNW; each active wave owns MTW x NTW 16x16 tiles.
// xin stride IPAD+4 (<=2-way or conflict-free rows); sc stride OPAD+1 (odd,
// conflict-free for both C-frag writes and pooled reads).
#define LD_A(dst, kk, iib)                                                   \
    _Pragma("unroll") for (int mi_ = 0; mi_ < MTW; ++mi_)                    \
        dst[mi_] = *(const short8*)(wfrag +                                  \
            (size_t)(((kk) * IB + (iib)) * (OPAD / 16) + otB + mi_) * 512);
#define LD_B(dst, kk, iib)                                                   \
    _Pragma("unroll") for (int ni_ = 0; ni_ < NTW; ++ni_) {                  \
        int tt_ = t0 + nBase + ni_ * 16 + l15 + (kk);                        \
        if (tt_ >= TIN) tt_ = TIN - 1;                                       \
        dst[ni_] = *(const short8*)(xin + tt_ * XSTR + (iib) * 32 + quad * 8); }
#define DO_MFMA(pa, pb)                                                      \
    _Pragma("unroll") for (int mi_ = 0; mi_ < MTW; ++mi_)                    \
    _Pragma("unroll") for (int ni_ = 0; ni_ < NTW; ++ni_)                    \
        acc[mi_][ni_] = __builtin_amdgcn_mfma_f32_16x16x32_bf16(             \
            pa[mi_], pb[ni_], acc[mi_][ni_], 0, 0, 0);

template<int OPAD, int IPAD, int IB, int WMW, int WNW, int MTW, int NTW,
         int NCHUNK, int NC, int TIN, int NPtot, bool LAST>
__device__ __forceinline__ void conv_layer(
    const short* __restrict__ wk, const float* __restrict__ bias,
    const short* xin, short* outT, float* feats, float* sc, int tid) {
    constexpr int XSTR = IPAD + 4;
    constexpr int OSTR = OPAD + 4;
    constexpr int SSTR = OPAD + 1;
    constexpr int PCc  = NCHUNK / 3;

    int w = tid >> 6, lane = tid & 63, l15 = lane & 15, quad = lane >> 4;
    bool act = (w < WMW * WNW);
    int otB = (w % WMW) * MTW;                 // otile base for A blocks
    int mBase = otB * 16;
    int nBase = (w / WMW) * NTW * 16;
    const short* wfrag = wk + lane * 8;        // lane's 16B within each block

    for (int nc = 0; nc < NC; ++nc) {
        int t0 = nc * NCHUNK;
        if (act) {
            f32x4 acc[MTW][NTW];
#pragma unroll
            for (int mi = 0; mi < MTW; ++mi)
#pragma unroll
                for (int ni = 0; ni < NTW; ++ni)
                    acc[mi][ni] = (f32x4){0.f, 0.f, 0.f, 0.f};

            short8 a0[MTW], b0[NTW], a1[MTW], b1[NTW];
            LD_A(a0, 0, 0)
            LD_B(b0, 0, 0)
#pragma unroll
            for (int t = 0; t < 10 * IB; t += 2) {   // (k,ib) pairs, ping-pong
                LD_A(a1, (t + 1) / IB, (t + 1) % IB)
                LD_B(b1, (t + 1) / IB, (t + 1) % IB)
                DO_MFMA(a0, b0)
                if (t + 2 < 10 * IB) {
                    LD_A(a0, (t + 2) / IB, (t + 2) % IB)
                    LD_B(b0, (t + 2) / IB, (t + 2) % IB)
                }
                DO_MFMA(a1, b1)
            }
            // C frags -> sc transposed: sc[col_local][o]
#pragma unroll
            for (int mi = 0; mi < MTW; ++mi)
#pragma unroll
                for (int ni = 0; ni < NTW; ++ni) {
                    int col = nBase + ni * 16 + l15;
                    int rb = mBase + mi * 16 + quad * 4;
#pragma unroll
                    for (int r = 0; r < 4; ++r)
                        sc[col * SSTR + rb + r] = acc[mi][ni][r];
                }
        }
        __syncthreads();
        // pool3 + bias + ELU + store (bf16 time-major LDS, or f32 feats)
        int pc0 = nc * PCc;
        for (int i = tid; i < PCc * OPAD; i += 512) {
            int tp = i / OPAD, ol = i - tp * OPAD;
            if (pc0 + tp < NPtot) {
                float s0 = sc[(tp * 3 + 0) * SSTR + ol];
                float s1 = sc[(tp * 3 + 1) * SSTR + ol];
                float s2 = sc[(tp * 3 + 2) * SSTR + ol];
                float m = fmaxf(fmaxf(s0, s1), s2) + bias[ol];
                float e = m > 0.f ? m : __expf(m) - 1.f;
                if constexpr (LAST) {
                    if (ol < 200) feats[ol * 7 + pc0 + tp] = e;
                } else {
                    outT[(pc0 + tp) * OSTR + ol] = f2bf(e);
                }
            }
        }
        __syncthreads();
    }
}

// ---- fused backbone + head: one block per sample --------------------------
// LDS overlay offsets (bytes); all 16-aligned. Peak 124,560 B (121.6 KB).
#define OFF_P2   0        // [107][68] bf16, live conv3-out .. conv4-in
#define OFF_P3   16000    // [32][132] bf16, live conv4-out .. conv5-in
#define OFF_FE   25600    // [1400] f32,     live conv5-out .. head
#define OFF_P1   72000    // [330][36] bf16, live conv12-out .. conv3-in
#define OFF_SC   95760    // f32 scratch (28800 B), reused by all layers
#define LDS_TOT  124560

__global__ __launch_bounds__(512, 1) void k_fused(
    const float* __restrict__ x, const int* __restrict__ sid,
    const short* __restrict__ wss, const float* __restrict__ wsf,
    const float* __restrict__ hW, const float* __restrict__ hB,
    float* __restrict__ out) {
    __shared__ __align__(16) unsigned char ldsbuf[LDS_TOT];
    short* xsAll = (short*)ldsbuf;              // [1000][36], dead after conv12
    short* P2    = (short*)(ldsbuf + OFF_P2);
    short* P3    = (short*)(ldsbuf + OFF_P3);
    float* feats = (float*)(ldsbuf + OFF_FE);
    short* P1    = (short*)(ldsbuf + OFF_P1);
    float* sc    = (float*)(ldsbuf + OFF_SC);

    int b = blockIdx.x;
    int tid = threadIdx.x;

    // ---- stage x[b] f32 [22][1000] -> xsAll bf16 time-major [1000][36] ----
    const float4* xb4 = reinterpret_cast<const float4*>(x + (size_t)b * 22000);
    for (int i = tid; i < 5500; i += 512) {     // 22 ch * 250 float4
        int c = i / 250, t4 = (i - c * 250) * 4;
        float4 v = xb4[i];
        xsAll[(t4 + 0) * 36 + c] = f2bf(v.x);
        xsAll[(t4 + 1) * 36 + c] = f2bf(v.y);
        xsAll[(t4 + 2) * 36 + c] = f2bf(v.z);
        xsAll[(t4 + 3) * 36 + c] = f2bf(v.w);
    }
    for (int i = tid; i < 10000; i += 512) {    // zero pad channels 22..31
        int c = 22 + i / 1000, t = i % 1000;
        xsAll[t * 36 + c] = 0;
    }
    __syncthreads();

    // conv12: M=32(25), N=990 -> 330 pooled; 6 chunks of 192
    conv_layer<32, 32, 1, 2, 4, 1, 3, 192, 6, 1000, 330, false>(
        wss + WK12, wsf + F_BC, xsAll, P1, nullptr, sc, tid);
    // conv3: M=64(50), N=321 -> 107 pooled; 4 chunks of 96
    conv_layer<64, 32, 1, 4, 2, 1, 3, 96, 4, 330, 107, false>(
        wss + WK3, wsf + F_B2, P1, P2, nullptr, sc, tid);
    // conv4: M=128(100), N=96 -> 32 pooled; 2 chunks of 48
    conv_layer<128, 64, 2, 8, 1, 1, 3, 48, 2, 107, 32, false>(
        wss + WK4, wsf + F_B3, P2, P3, nullptr, sc, tid);
    // conv5: M=224(200), N=21 -> 7 pooled; 1 chunk of 32 (waves 0-6 active)
    conv_layer<224, 128, 4, 7, 1, 2, 2, 32, 1, 32, 7, true>(
        wss + WK5, wsf + F_B4, P3, nullptr, feats, sc, tid);

    // ---- head: per-sample routed linear, wave w -> output w (w<4) ----
    int w = tid >> 6, lane = tid & 63;
    if (w < 4) {
        int s = sid[b];
        const float4* wrow = reinterpret_cast<const float4*>(hW + (size_t)(s * 4 + w) * 1400);
        const float4* fv = reinterpret_cast<const float4*>(feats);
        float acc = 0.f;
        for (int f = lane; f < 350; f += 64) {
            float4 a = wrow[f], c = fv[f];
            acc += a.x * c.x + a.y * c.y + a.z * c.z + a.w * c.w;
        }
#pragma unroll
        for (int off = 32; off; off >>= 1) acc += __shfl_down(acc, off);
        if (lane == 0) out[b * 4 + w] = acc + hB[s * 4 + w];
    }
}

extern "C" void kernel_launch(void* const* d_in, const int* in_sizes, int n_in,
                              void* d_out, int out_size, void* d_ws, size_t ws_size,
                              hipStream_t stream) {
    const float* x   = (const float*)d_in[0];
    const int*   sid = (const int*)d_in[1];
    const float* wt  = (const float*)d_in[2];
    const float* bt  = (const float*)d_in[3];
    const float* wsp = (const float*)d_in[4];
    const float* bsp = (const float*)d_in[5];
    const float* w2  = (const float*)d_in[6];
    const float* b2  = (const float*)d_in[7];
    const float* w3  = (const float*)d_in[8];
    const float* b3  = (const float*)d_in[9];
    const float* w4  = (const float*)d_in[10];
    const float* b4  = (const float*)d_in[11];
    const float* hW  = (const float*)d_in[12];
    const float* hB  = (const float*)d_in[13];
    float* out = (float*)d_out;
    float* wsf = (float*)d_ws;
    short* wss = (short*)d_ws + SHORT_BASE;

    // prep: block 0 = biases; blocks 1..1560 = 399360 weight elements
    k_prep2<<<1561, 256, 0, stream>>>(wt, bt, wsp, bsp, w2, b2, w3, b3, w4, b4,
                                      wsf, wss);
    // fused backbone + head: 1 block per sample, 8 waves, 121.6 KB LDS
    k_fused<<<256, 512, 0, stream>>>(x, sid, wss, wsf, hW, hB, out);
}

// Round 4
// 148.697 us; speedup vs baseline: 1.4979x; 1.4533x over previous
//
#include <hip/hip_runtime.h>
#include <math.h>

// ---------------------------------------------------------------------------
// Deep4Net via bf16 MFMA (fp32 accum). Multi-kernel (one launch per layer),
// high-occupancy: each layer kernel runs 1792-2816 blocks, ~20-40KB LDS ->
// many blocks/CU, latency hidden by TLP (the fused 1-block/CU variant was
// latency-starved at 133us; this structure's conv total is ~40-60us).
// conv1+conv2 fused algebraically; pool(elu)=elu(pool).
//   out[o][t] += sum_i wk[k][o][i] * xT[t+k][i]
// Weights FRAGMENT-ORDERED by prep: for each (k, ib, otile) a 512-short
// block where lane l holds shorts [l*8..+7] = its exact MFMA A-fragment ->
// wave A-load = one coalesced 1KB global_load_dwordx4 (was 16-line gather).
// B-frag: xT[t][i: quad*8..+7] staged in LDS (ds_read_b128, rows padded +4).
// Epilogue scratch sc stored transposed [col][o] with odd stride MSPAN+1.
//
// Workspace: float region then short(bf16) region.
#define F_BC   0         // 32   combined bias (padded)
#define F_B2   32        // 64
#define F_B3   96        // 128
#define F_B4   224       // 224
#define F_P4   448       // 256*1400 f32 features
#define SHORT_BASE 717696  // short index of bf16 region
#define WK12   0         // [10][1][2][512]   (k, ib, otile, frag)
#define WK3    10240     // [10][1][4][512]
#define WK4    30720     // [10][2][8][512]
#define WK5    112640    // [10][4][14][512]
#define P1T    399360    // [256][330][32]
#define P2T    3102720   // [256][107][64]
#define P3T    4855808   // [256][32][128]
// ---------------------------------------------------------------------------

typedef __attribute__((ext_vector_type(8))) short short8;
typedef __attribute__((ext_vector_type(4))) float f32x4;

__device__ __forceinline__ short f2bf(float f) {
    union { float f; unsigned u; } v; v.f = f;
    unsigned r = v.u + 0x7FFF + ((v.u >> 16) & 1);
    return (short)(r >> 16);
}

// ---- K0: weight prep --------------------------------------------------------
// block 0: biases (combined conv1/2 bias via LDS-atomic reduction over 625
// (o,i) pairs -- the old serial 25-thread version was ~70-90us!).
// blocks 1..1560: fragment-ordered bf16 weight transpose (399360 elems).
__global__ __launch_bounds__(256) void k_prep2(
    const float* __restrict__ wt, const float* __restrict__ bt,
    const float* __restrict__ wsp, const float* __restrict__ bsp,
    const float* __restrict__ w2, const float* __restrict__ b2,
    const float* __restrict__ w3, const float* __restrict__ b3,
    const float* __restrict__ w4, const float* __restrict__ b4,
    float* __restrict__ wsf, short* __restrict__ wss) {
    int tid = threadIdx.x;
    if (blockIdx.x == 0) {
        __shared__ float bacc[32];
        if (tid < 32) bacc[tid] = 0.f;
        __syncthreads();
        for (int p = tid; p < 625; p += 256) {      // combined bias reduction
            int o = p / 25, i = p - o * 25;
            float rs = 0.f;
            for (int c = 0; c < 22; ++c) rs += wsp[(o * 25 + i) * 22 + c];
            atomicAdd(&bacc[o], bt[i] * rs);
        }
        __syncthreads();
        for (int idx = tid; idx < 448; idx += 256) {
            float v;
            if (idx < 32)        v = (idx < 25) ? bsp[idx] + bacc[idx] : 0.f;
            else if (idx < 96)  { int o = idx - 32;  v = (o < 50)  ? b2[o] : 0.f; }
            else if (idx < 224) { int o = idx - 96;  v = (o < 100) ? b3[o] : 0.f; }
            else                { int o = idx - 224; v = (o < 200) ? b4[o] : 0.f; }
            wsf[idx] = v;
        }
        return;
    }
    int j = (blockIdx.x - 1) * 256 + tid;
    if (j < 10240) {                           // wk12 combined: OPAD=32, IB=1
        int g = j >> 9, s = j & 511;
        int k = g >> 1, ot = g & 1;
        int lane = s >> 3, e = s & 7;
        int o = ot * 16 + (lane & 15), i = (lane >> 4) * 8 + e;
        float v = 0.f;
        if (o < 25 && i < 22)
            for (int q = 0; q < 25; ++q) v += wt[q * 10 + k] * wsp[(o * 25 + q) * 22 + i];
        wss[WK12 + j] = f2bf(v);
        return;
    }
    j -= 10240;
    if (j < 20480) {                           // wk3: OPAD=64, IB=1 (4 blk/k)
        int g = j >> 9, s = j & 511;
        int k = g >> 2, ot = g & 3;
        int lane = s >> 3, e = s & 7;
        int o = ot * 16 + (lane & 15), i = (lane >> 4) * 8 + e;
        float v = (o < 50 && i < 25) ? w2[(o * 25 + i) * 10 + k] : 0.f;
        wss[WK3 + j] = f2bf(v);
        return;
    }
    j -= 20480;
    if (j < 81920) {                           // wk4: OPAD=128, IB=2 (16 blk/k)
        int g = j >> 9, s = j & 511;
        int k = g >> 4, rem = g & 15, ib = rem >> 3, ot = rem & 7;
        int lane = s >> 3, e = s & 7;
        int o = ot * 16 + (lane & 15), i = ib * 32 + (lane >> 4) * 8 + e;
        float v = (o < 100 && i < 50) ? w3[(o * 50 + i) * 10 + k] : 0.f;
        wss[WK4 + j] = f2bf(v);
        return;
    }
    j -= 81920;
    if (j < 286720) {                          // wk5: OPAD=224, IB=4 (56 blk/k)
        int g = j >> 9, s = j & 511;
        int k = g / 56, rem = g % 56, ib = rem / 14, ot = rem % 14;
        int lane = s >> 3, e = s & 7;
        int o = ot * 16 + (lane & 15), i = ib * 32 + (lane >> 4) * 8 + e;
        float v = (o < 200 && i < 100) ? w4[(o * 100 + i) * 10 + k] : 0.f;
        wss[WK5 + j] = f2bf(v);
    }
}

// ---- generic MFMA conv+pool+ELU layer -------------------------------------
// block = 4 waves: wave w -> (m-tile w%WM, n-group w/WM of NT 16-wide tiles)
// grid: idx = b + 256*(nc + NC*mc)
template<int OPAD, int IPAD, int IB, int WM, int NT, int NCHUNK, bool F32IN, bool LAST>
__global__ __launch_bounds__(256) void k_cmfma(
    const short* __restrict__ wk, const float* __restrict__ bias,
    const short* __restrict__ xinT, const float* __restrict__ xf32,
    short* __restrict__ outT, float* __restrict__ p4,
    int NC, int TIN, int NPtot) {
    constexpr int ROWS = NCHUNK + 9;
    constexpr int MSPAN = WM * 16;
    constexpr int XSTR = IPAD + 4;      // +4 shorts: bank-conflict-free rows
    constexpr int SSTR = MSPAN + 1;     // odd stride: conflict-free sc
    __shared__ short xs[ROWS * XSTR];
    __shared__ float sc[NCHUNK * SSTR];

    int idx = blockIdx.x;
    int b = idx % 256;
    int nc = (idx / 256) % NC;
    int mc = idx / (256 * NC);
    int t0 = nc * NCHUNK;
    int tid = threadIdx.x;

    // ---- stage input tile into LDS (bf16, time-major) ----
    if constexpr (F32IN) {
        // x[b][c][t] f32 -> xs[r*XSTR + c]; pad c>=22 with 0
        const float* xb = xf32 + b * 22000;
        for (int i = tid; i < 32 * 128; i += 256) {
            int c = i >> 7, r = i & 127;
            if (r < ROWS) {
                short v = 0;
                if (c < 22) {
                    int t = t0 + r; if (t > 999) t = 999;
                    v = f2bf(xb[c * 1000 + t]);
                }
                xs[r * XSTR + c] = v;
            }
        }
    } else {
        const short* xb = xinT + (size_t)b * TIN * IPAD;
        constexpr int V = IPAD / 8;
        for (int i = tid; i < ROWS * V; i += 256) {
            int r = i / V, vv = i - r * V;
            int t = t0 + r; if (t >= TIN) t = TIN - 1;   // clamp; extras discarded
            *(short8*)(xs + r * XSTR + vv * 8) =
                *(const short8*)(xb + (size_t)t * IPAD + vv * 8);
        }
    }
    __syncthreads();

    int w = tid >> 6, lane = tid & 63, l15 = lane & 15, quad = lane >> 4;
    int mt = w % WM, ns = w / WM;
    int otg = mc * WM + mt;             // global otile index for A blocks
    int tw = ns * NT * 16;

    f32x4 acc[NT];
#pragma unroll
    for (int i = 0; i < NT; ++i) acc[i] = (f32x4){0.f, 0.f, 0.f, 0.f};

    const short* wfrag = wk + lane * 8; // lane's 16B within each 512-short block
#pragma unroll 2
    for (int k = 0; k < 10; ++k) {
#pragma unroll
        for (int ib = 0; ib < IB; ++ib) {
            short8 a = *(const short8*)(wfrag +
                (size_t)((k * IB + ib) * (OPAD / 16) + otg) * 512);
#pragma unroll
            for (int nt = 0; nt < NT; ++nt) {
                short8 bf = *(const short8*)(xs + (tw + nt * 16 + l15 + k) * XSTR +
                                             ib * 32 + quad * 8);
                acc[nt] = __builtin_amdgcn_mfma_f32_16x16x32_bf16(a, bf, acc[nt], 0, 0, 0);
            }
        }
    }

    // ---- C frags -> LDS f32 scratch, transposed: sc[col][o_local] ----
#pragma unroll
    for (int nt = 0; nt < NT; ++nt) {
        int col = tw + nt * 16 + l15;
        int rbase = mt * 16 + quad * 4;
#pragma unroll
        for (int r = 0; r < 4; ++r)
            sc[col * SSTR + rbase + r] = acc[nt][r];
    }
    __syncthreads();

    // ---- pool3 + bias + ELU + store (bf16 transposed, or f32 feats) ----
    constexpr int PC = NCHUNK / 3;
    int pc0 = nc * PC;
    for (int i = tid; i < PC * MSPAN; i += 256) {
        int tp = i / MSPAN, ol = i - tp * MSPAN;
        if (pc0 + tp < NPtot) {
            float s0 = sc[(tp * 3 + 0) * SSTR + ol];
            float s1 = sc[(tp * 3 + 1) * SSTR + ol];
            float s2 = sc[(tp * 3 + 2) * SSTR + ol];
            float m = fmaxf(fmaxf(s0, s1), s2) + bias[mc * MSPAN + ol];
            float e = m > 0.f ? m : __expf(m) - 1.f;
            if constexpr (LAST) {
                int o = mc * MSPAN + ol;
                if (o < 200) p4[(size_t)b * 1400 + o * 7 + (pc0 + tp)] = e;
            } else {
                outT[(size_t)b * NPtot * OPAD + (size_t)(pc0 + tp) * OPAD +
                     mc * MSPAN + ol] = f2bf(e);
            }
        }
    }
}

// ---- head: per-sample routed linear, one wave per output, f32 -------------
__global__ __launch_bounds__(256) void k_head(const float* __restrict__ hW,
                                              const float* __restrict__ hB,
                                              const int* __restrict__ sid,
                                              const float* __restrict__ p4,
                                              float* __restrict__ out) {
    int b = blockIdx.x;
    int tid = threadIdx.x;
    int wave = tid >> 6, lane = tid & 63;
    int sidb = sid[b];
    const float4* wrow = reinterpret_cast<const float4*>(hW + (sidb * 4 + wave) * 1400);
    const float4* feat = reinterpret_cast<const float4*>(p4 + b * 1400);
    float acc = 0.f;
    for (int f = lane; f < 350; f += 64) {
        float4 a = wrow[f], c = feat[f];
        acc += a.x * c.x + a.y * c.y + a.z * c.z + a.w * c.w;
    }
#pragma unroll
    for (int off = 32; off; off >>= 1) acc += __shfl_down(acc, off);
    if (lane == 0) out[b * 4 + wave] = acc + hB[sidb * 4 + wave];
}

extern "C" void kernel_launch(void* const* d_in, const int* in_sizes, int n_in,
                              void* d_out, int out_size, void* d_ws, size_t ws_size,
                              hipStream_t stream) {
    const float* x   = (const float*)d_in[0];
    const int*   sid = (const int*)d_in[1];
    const float* wt  = (const float*)d_in[2];
    const float* bt  = (const float*)d_in[3];
    const float* wsp = (const float*)d_in[4];
    const float* bsp = (const float*)d_in[5];
    const float* w2  = (const float*)d_in[6];
    const float* b2  = (const float*)d_in[7];
    const float* w3  = (const float*)d_in[8];
    const float* b3  = (const float*)d_in[9];
    const float* w4  = (const float*)d_in[10];
    const float* b4  = (const float*)d_in[11];
    const float* hW  = (const float*)d_in[12];
    const float* hB  = (const float*)d_in[13];
    float* out = (float*)d_out;
    float* wsf = (float*)d_ws;
    short* wss = (short*)d_ws + SHORT_BASE;

    // prep: block 0 = biases; blocks 1..1560 = 399360 weight elements
    k_prep2<<<1561, 256, 0, stream>>>(wt, bt, wsp, bsp, w2, b2, w3, b3, w4, b4,
                                      wsf, wss);
    // conv12: M=32(25), N=990 unpooled -> 330 pooled; 11 n-chunks of 96
    k_cmfma<32, 32, 1, 2, 3, 96, true, false><<<256 * 11, 256, 0, stream>>>(
        wss + WK12, wsf + F_BC, nullptr, x, wss + P1T, nullptr, 11, 1000, 330);
    // conv3: M=64(50), 107 pooled; 7 n-chunks of 48
    k_cmfma<64, 32, 1, 4, 3, 48, false, false><<<256 * 7, 256, 0, stream>>>(
        wss + WK3, wsf + F_B2, wss + P1T, nullptr, wss + P2T, nullptr, 7, 330, 107);
    // conv4: M=128(100) in 2 m-chunks, 32 pooled; 2 n-chunks of 48
    k_cmfma<128, 64, 2, 4, 3, 48, false, false><<<256 * 2 * 2, 256, 0, stream>>>(
        wss + WK4, wsf + F_B3, wss + P2T, nullptr, wss + P3T, nullptr, 2, 107, 32);
    // conv5: M=224(200) in 7 m-chunks, 7 pooled; 1 n-chunk of 32
    k_cmfma<224, 128, 4, 2, 1, 32, false, true><<<256 * 7, 256, 0, stream>>>(
        wss + WK5, wsf + F_B4, wss + P3T, nullptr, nullptr, wsf + F_P4, 1, 32, 7);
    k_head<<<256, 256, 0, stream>>>(hW, hB, sid, wsf + F_P4, out);
}